// Round 1
// baseline (155.829 us; speedup 1.0000x reference)
//
#include <hip/hip_runtime.h>

// Canvas geometry from the reference.
#define CANVAS_H 6144
#define CANVAS_W 6144
#define LINE_WIDTH 1.0f
#define PIX_PER_THREAD 4
#define BLOCK 256

__global__ __launch_bounds__(BLOCK) void
LineRaster2d_kernel(const float* __restrict__ p0g,
                    const float* __restrict__ p1g,
                    float* __restrict__ out) {
    const long long tid  = (long long)blockIdx.x * BLOCK + threadIdx.x;
    const long long base = tid * PIX_PER_THREAD;   // flat pixel index of first of 4

    // x = row (first canvas axis), y = column. W divisible by 4, so the 4
    // pixels of one thread always share a row.
    const int x  = (int)(base / CANVAS_W);
    const int y0 = (int)(base % CANVAS_W);

    // Uniform scalar setup (compiler lifts these to scalar loads / SALU).
    const float p0x = p0g[0] * (float)CANVAS_H;
    const float p0y = p0g[1] * (float)CANVAS_W;
    const float p1x = p1g[0] * (float)CANVAS_H;
    const float p1y = p1g[1] * (float)CANVAS_W;
    const float dx = p1x - p0x;
    const float dy = p1y - p0y;
    const float inv_len_sq = 1.0f / (dx * dx + dy * dy);

    const float px = (float)x - p0x;
    const float px_dx = px * dx;

    float4 r;
    float* rp = &r.x;
#pragma unroll
    for (int j = 0; j < PIX_PER_THREAD; ++j) {
        const float py = (float)(y0 + j) - p0y;
        float t = (px_dx + py * dy) * inv_len_sq;
        t = fminf(fmaxf(t, 0.0f), 1.0f);
        const float ex = px - t * dx;      // X - proj_x
        const float ey = py - t * dy;      // Y - proj_y
        const float dist = sqrtf(ex * ex + ey * ey);
        rp[j] = (dist < LINE_WIDTH) ? (LINE_WIDTH - dist) : 0.0f;
    }

    *reinterpret_cast<float4*>(out + base) = r;
}

extern "C" void kernel_launch(void* const* d_in, const int* in_sizes, int n_in,
                              void* d_out, int out_size, void* d_ws, size_t ws_size,
                              hipStream_t stream) {
    const float* p0 = (const float*)d_in[0];
    const float* p1 = (const float*)d_in[1];
    float* out = (float*)d_out;

    const long long n_pix = (long long)CANVAS_H * CANVAS_W;   // == out_size
    const int n_blocks = (int)(n_pix / (PIX_PER_THREAD * BLOCK));

    LineRaster2d_kernel<<<n_blocks, BLOCK, 0, stream>>>(p0, p1, out);
}

// Round 2
// 148.976 us; speedup vs baseline: 1.0460x; 1.0460x over previous
//
#include <hip/hip_runtime.h>

// Canvas geometry from the reference.
#define CANVAS_H 6144
#define CANVAS_W 6144
#define BLOCK 256

__global__ __launch_bounds__(BLOCK) void
LineRaster2d_kernel(const float* __restrict__ p0g,
                    const float* __restrict__ p1g,
                    float* __restrict__ out) {
    const int tid  = blockIdx.x * BLOCK + threadIdx.x;
    const int base = tid * 4;                    // fits in int32 (37.7M < 2^31)

    // W % 4 == 0, so the 4 pixels of one thread always share a row.
    const int x  = (int)((unsigned)base / CANVAS_W);   // magic-mul, no HW divide
    const int y0 = base - x * CANVAS_W;

    // Uniform setup (scalar loads / SALU): endpoints in pixel coords.
    const float p0x = p0g[0] * (float)CANVAS_H;
    const float p0y = p0g[1] * (float)CANVAS_W;
    const float dx  = p1g[0] * (float)CANVAS_H - p0x;
    const float dy  = p1g[1] * (float)CANVAS_W - p0y;
    // v_rcp_f32: ~1 ulp, far within the 2e-2 absmax budget.
    const float inv_len_sq = __builtin_amdgcn_rcpf(dx * dx + dy * dy);

    const float px = (float)x - p0x;

    // ---- Conservative reject: distance from group center (x, y0+1.5) to the
    // segment. Point-to-segment distance is 1-Lipschitz in the query point and
    // the farthest pixel center is 1.5 away, so dist_center >= 2.5 implies all
    // four pixels have dist >= 1 (output 0). Test against 3.0 (squared: 9) for
    // 0.5 of fp-rounding margin.
    const float pyc = ((float)y0 + 1.5f) - p0y;
    float tc = (px * dx + pyc * dy) * inv_len_sq;
    tc = fminf(fmaxf(tc, 0.0f), 1.0f);
    const float ecx = px - tc * dx;
    const float ecy = pyc - tc * dy;
    const float d2c = ecx * ecx + ecy * ecy;

    float4 r = make_float4(0.0f, 0.0f, 0.0f, 0.0f);
    if (d2c < 9.0f) {                 // taken by ~0.1% of waves -> execz skip
        const float px_dx = px * dx;
        float py, t, ex, ey, dist;

        py = (float)(y0 + 0) - p0y;
        t  = fminf(fmaxf((px_dx + py * dy) * inv_len_sq, 0.0f), 1.0f);
        ex = px - t * dx;  ey = py - t * dy;
        dist = __builtin_amdgcn_sqrtf(ex * ex + ey * ey);
        r.x = (dist < 1.0f) ? (1.0f - dist) : 0.0f;

        py = (float)(y0 + 1) - p0y;
        t  = fminf(fmaxf((px_dx + py * dy) * inv_len_sq, 0.0f), 1.0f);
        ex = px - t * dx;  ey = py - t * dy;
        dist = __builtin_amdgcn_sqrtf(ex * ex + ey * ey);
        r.y = (dist < 1.0f) ? (1.0f - dist) : 0.0f;

        py = (float)(y0 + 2) - p0y;
        t  = fminf(fmaxf((px_dx + py * dy) * inv_len_sq, 0.0f), 1.0f);
        ex = px - t * dx;  ey = py - t * dy;
        dist = __builtin_amdgcn_sqrtf(ex * ex + ey * ey);
        r.z = (dist < 1.0f) ? (1.0f - dist) : 0.0f;

        py = (float)(y0 + 3) - p0y;
        t  = fminf(fmaxf((px_dx + py * dy) * inv_len_sq, 0.0f), 1.0f);
        ex = px - t * dx;  ey = py - t * dy;
        dist = __builtin_amdgcn_sqrtf(ex * ex + ey * ey);
        r.w = (dist < 1.0f) ? (1.0f - dist) : 0.0f;
    }

    // One fully-coalesced 16B store per lane: 1 KB per wave per instruction.
    *reinterpret_cast<float4*>(out + base) = r;
}

extern "C" void kernel_launch(void* const* d_in, const int* in_sizes, int n_in,
                              void* d_out, int out_size, void* d_ws, size_t ws_size,
                              hipStream_t stream) {
    const float* p0 = (const float*)d_in[0];
    const float* p1 = (const float*)d_in[1];
    float* out = (float*)d_out;

    const long long n_pix = (long long)CANVAS_H * CANVAS_W;   // == out_size
    const int n_blocks = (int)(n_pix / (4 * BLOCK));          // 36,864

    LineRaster2d_kernel<<<n_blocks, BLOCK, 0, stream>>>(p0, p1, out);
}